// Round 3
// baseline (100.279 us; speedup 1.0000x reference)
//
#include <hip/hip_runtime.h>
#include <stdint.h>

// Problem constants: B=8, Q=2048, D=256, H=8, L=3, P=4, HD=32
// vproj rows: level-major, T={2048,1024,512}, LOFF={0,16384,24576}, total 28672

typedef __attribute__((ext_vector_type(8))) short bf16x8;
typedef __attribute__((ext_vector_type(8))) unsigned short u16x8;
typedef __attribute__((ext_vector_type(4))) float f32x4;

__device__ __forceinline__ unsigned short f2bf(float f) {
    union { float f; uint32_t u; } v; v.f = f;
    return (unsigned short)((v.u + 0x7FFFu + ((v.u >> 16) & 1u)) >> 16);  // RNE
}
__device__ __forceinline__ float bf2f(unsigned short u) {
    union { uint32_t u; float f; } v; v.u = ((uint32_t)u) << 16;
    return v.f;
}

// C[M,N] = A @ B + bias, bf16 MFMA inside (f32 accum).
// A selected from {A0,A1,A2} by global row (fused multi-level value projection).
// Block tile 128x128, BK=32, 4 waves (2x2), wave tile 64x64.
// LDS: subtiled [slot][row][8k]; fragment reads are conflict-free ds_read_b128.
// A_BF16:  A matrices are bf16 (ushort), staged with 16B copies, no convert.
// OUT_BF16: C is bf16 (ushort), stores f2bf(acc+bias).
// CONCAT_B: B is the concatenation [B0 | B1 | 0] along columns (ldb per part),
//           bias likewise [bias0 | bias1] (cols >= 192 never stored).
template<bool A_BF16, bool OUT_BF16, bool CONCAT_B>
__global__ __launch_bounds__(256) void gemm_mfma_kernel(
    const void* __restrict__ A0v, const void* __restrict__ A1v, const void* __restrict__ A2v,
    int s0, int s1, int lda,
    const float* __restrict__ B0, const float* __restrict__ B1, int ldb,
    const float* __restrict__ bias0, const float* __restrict__ bias1,
    void* __restrict__ Cv, int ldc, int Nstore, int K)
{
    __shared__ unsigned short Asub[4][128][8];  // 8 KB
    __shared__ unsigned short Bsub[4][128][8];  // 8 KB

    const int t = threadIdx.x;
    const int row0 = blockIdx.y * 128;
    const int col0 = blockIdx.x * 128;

    const void* Ap; int arow;
    if (row0 < s0)      { Ap = A0v; arow = row0; }
    else if (row0 < s1) { Ap = A1v; arow = row0 - s0; }
    else                { Ap = A2v; arow = row0 - s1; }

    const int ar = t >> 1, ah = t & 1;        // A staging: row, k-half
    const int bc = t & 127, bq = t >> 7;      // B staging: col, slot-pair

    const int w = t >> 6, lane = t & 63;
    const int wr = w >> 1, wc = w & 1;        // wave 2x2 -> 64x64 tile
    const int fr = lane & 15, sl = lane >> 4; // fragment row/col + k-slot

    f32x4 acc[4][4];
#pragma unroll
    for (int m = 0; m < 4; ++m)
#pragma unroll
        for (int n = 0; n < 4; ++n) acc[m][n] = (f32x4){0.f, 0.f, 0.f, 0.f};

    for (int k0 = 0; k0 < K; k0 += 32) {
#pragma unroll
        for (int q = 0; q < 2; ++q) {           // stage A
            const int slot = ah * 2 + q;        // k = k0 + slot*8 .. +7
            if (A_BF16) {
                const unsigned short* Aps = (const unsigned short*)Ap;
                *reinterpret_cast<u16x8*>(&Asub[slot][ar][0]) =
                    *reinterpret_cast<const u16x8*>(&Aps[(size_t)(arow + ar) * lda + k0 + slot * 8]);
            } else {
                const float* Apf = (const float*)Ap;
                const float4 f0 = *reinterpret_cast<const float4*>(
                    &Apf[(size_t)(arow + ar) * lda + k0 + slot * 8]);
                const float4 f1 = *reinterpret_cast<const float4*>(
                    &Apf[(size_t)(arow + ar) * lda + k0 + slot * 8 + 4]);
                u16x8 pk;
                pk[0]=f2bf(f0.x); pk[1]=f2bf(f0.y); pk[2]=f2bf(f0.z); pk[3]=f2bf(f0.w);
                pk[4]=f2bf(f1.x); pk[5]=f2bf(f1.y); pk[6]=f2bf(f1.z); pk[7]=f2bf(f1.w);
                *reinterpret_cast<u16x8*>(&Asub[slot][ar][0]) = pk;
            }
        }
#pragma unroll
        for (int q = 0; q < 2; ++q) {           // stage B transposed (k-contig per col)
            const int slot = bq * 2 + q;
            const int col = col0 + bc;
            u16x8 pk;
#pragma unroll
            for (int j = 0; j < 8; ++j) {
                const int kk = k0 + slot * 8 + j;
                float v;
                if (CONCAT_B) {
                    v = (col < 96) ? B0[(size_t)kk * ldb + col]
                      : (col < 192) ? B1[(size_t)kk * ldb + (col - 96)]
                      : 0.f;
                } else {
                    v = B0[(size_t)kk * ldb + col];
                }
                pk[j] = f2bf(v);
            }
            *reinterpret_cast<u16x8*>(&Bsub[slot][bc][0]) = pk;
        }
        __syncthreads();

        bf16x8 bfrag[4];
#pragma unroll
        for (int n = 0; n < 4; ++n)
            bfrag[n] = *reinterpret_cast<bf16x8*>(&Bsub[sl][wc * 64 + n * 16 + fr][0]);
#pragma unroll
        for (int m = 0; m < 4; ++m) {
            bf16x8 afrag = *reinterpret_cast<bf16x8*>(&Asub[sl][wr * 64 + m * 16 + fr][0]);
#pragma unroll
            for (int n = 0; n < 4; ++n)
                acc[m][n] = __builtin_amdgcn_mfma_f32_16x16x32_bf16(afrag, bfrag[n], acc[m][n], 0, 0, 0);
        }
        __syncthreads();
    }

    // C/D layout (m89-verified): col = lane&15, row = (lane>>4)*4 + reg
#pragma unroll
    for (int n = 0; n < 4; ++n) {
        const int col = col0 + wc * 64 + n * 16 + fr;
        if (col >= Nstore) continue;
        const float bs = CONCAT_B ? ((col < 96) ? bias0[col] : bias1[col - 96]) : bias0[col];
#pragma unroll
        for (int m = 0; m < 4; ++m) {
            const int r = row0 + wr * 64 + m * 16 + sl * 4;
#pragma unroll
            for (int j = 0; j < 4; ++j) {
                if (OUT_BF16)
                    ((unsigned short*)Cv)[(size_t)(r + j) * ldc + col] = f2bf(acc[m][n][j] + bs);
                else
                    ((float*)Cv)[(size_t)(r + j) * ldc + col] = acc[m][n][j] + bs;
            }
        }
    }
}

// per query: softmax the aw logits per-head (12-wide) and turn offsets into
// sample indices. rows layout per query (ld=192): GEMM wrote [0..95]=off
// logits, [96..191]=aw logits; we write [0..95]=aw, [96..191]=sidx.
__global__ __launch_bounds__(128) void softmax_sidx_kernel(
    const float* __restrict__ refpts, float* __restrict__ rows)
{
    const int bq = blockIdx.x;
    const int t = threadIdx.x;
    float* row = rows + (size_t)bq * 192;
    __shared__ float soff[96];
    __shared__ float sl[96];
    __shared__ float hm[8], hs[8];
    if (t < 96) { soff[t] = row[t]; sl[t] = row[96 + t]; }
    __syncthreads();
    if (t < 8) {
        float m = -1e30f;
        for (int j = 0; j < 12; ++j) m = fmaxf(m, sl[t * 12 + j]);
        hm[t] = m;
    }
    __syncthreads();
    if (t < 96) sl[t] = expf(sl[t] - hm[t / 12]);
    __syncthreads();
    if (t < 8) {
        float s = 0.f;
        for (int j = 0; j < 12; ++j) s += sl[t * 12 + j];
        hs[t] = s;
    }
    __syncthreads();
    if (t < 96) {
        row[t] = sl[t] / hs[t / 12];              // aw
        const int l = (t % 12) >> 2;
        const int T = 2048 >> l;
        const float ref = refpts[bq];
        float pos = ref + soff[t] / (float)T;
        pos = fminf(fmaxf(pos, 0.f), 1.f);
        row[96 + t] = pos * (float)(T - 1);        // sidx
    }
}

// gather + lerp + weighted sum:  omid[bq, h*32+c] = sum_{l,p} aw * lerp(vproj)
// XCD-locality: bq = (bid&7)*2048 + (bid>>3)  ->  all blocks on one XCD share
// one batch b, whose bf16 vproj slice (1.84 MB) is L2-resident.
__global__ __launch_bounds__(256) void sample_kernel(
    const float* __restrict__ rows,            // [16384,192]  aw | sidx
    const unsigned short* __restrict__ vproj,  // [28672,128]  bf16, level-major
    unsigned short* __restrict__ out_mid)      // [16384,256]  bf16
{
    const int bid = blockIdx.x;
    const int bq = ((bid & 7) << 11) | (bid >> 3);
    const int b = bq >> 11;
    const int t = threadIdx.x;
    const int h = t >> 5, c = t & 31;
    __shared__ float srow[192];
    if (t < 192) srow[t] = rows[(size_t)bq * 192 + t];
    __syncthreads();
    float acc = 0.f;
#pragma unroll
    for (int l = 0; l < 3; ++l) {
        const int T = 2048 >> l;
        const int loff = (l == 0) ? 0 : ((l == 1) ? 16384 : 24576);
#pragma unroll
        for (int p = 0; p < 4; ++p) {
            const int j = h * 12 + l * 4 + p;
            const float w = srow[j];
            const float sidx = srow[96 + j];
            int ifl = (int)sidx;
            ifl = min(max(ifl, 0), T - 2);
            const float wce = sidx - (float)ifl;
            const size_t base = ((size_t)(loff + b * T + ifl)) * 128 + p * 32 + c;
            const float vf = bf2f(vproj[base]);
            const float vc = bf2f(vproj[base + 128]);
            acc += w * (vf + wce * (vc - vf));
        }
    }
    out_mid[(size_t)bq * 256 + t] = f2bf(acc);
}

extern "C" void kernel_launch(void* const* d_in, const int* in_sizes, int n_in,
                              void* d_out, int out_size, void* d_ws, size_t ws_size,
                              hipStream_t stream) {
    (void)in_sizes; (void)n_in; (void)out_size; (void)ws_size;
    const float* query = (const float*)d_in[0];
    const float* refp  = (const float*)d_in[1];
    const float* v0    = (const float*)d_in[2];
    const float* v1    = (const float*)d_in[3];
    const float* v2    = (const float*)d_in[4];
    const float* Woff  = (const float*)d_in[5];
    const float* boff  = (const float*)d_in[6];
    const float* Waw   = (const float*)d_in[7];
    const float* baw   = (const float*)d_in[8];
    const float* Wv    = (const float*)d_in[9];
    const float* bv    = (const float*)d_in[10];
    const float* Wo    = (const float*)d_in[11];
    const float* bo    = (const float*)d_in[12];
    float* out = (float*)d_out;

    char* ws = (char*)d_ws;
    unsigned short* vproj = (unsigned short*)(ws);                 // 28672*128*2 = 7,340,032 B
    float*          rows  = (float*)(ws + 7340032);                // 16384*192*4 = 12,582,912 B
    unsigned short* omid  = (unsigned short*)(ws + 7340032 + 12582912); // 16384*256*2 = 8,388,608 B

    const int HUGE = 1 << 30;

    // K1: fused value projections (all 3 levels, one launch), bf16 output.
    // Only cols 0..127 of Wv are consumed (reference gathers head axis by p<4).
    gemm_mfma_kernel<false, true, false><<<dim3(1, 224), 256, 0, stream>>>(
        v0, v1, v2, 16384, 24576, 256, Wv, nullptr, 256, bv, nullptr,
        vproj, 128, 128, 256);

    // K2a: offset + attention-weight logits; B = [Woff|Waw|0] staged on the fly.
    gemm_mfma_kernel<false, false, true><<<dim3(2, 128), 256, 0, stream>>>(
        query, query, query, HUGE, HUGE, 256, Woff, Waw, 96, boff, baw,
        rows, 192, 192, 256);

    // K2b: per-head softmax + sample index computation
    softmax_sidx_kernel<<<16384, 128, 0, stream>>>(refp, rows);

    // K3: gather + lerp + weighted sum (XCD-swizzled, bf16 in/out)
    sample_kernel<<<16384, 256, 0, stream>>>(rows, vproj, omid);

    // K4: output projection (A read directly as bf16)
    gemm_mfma_kernel<true, false, false><<<dim3(2, 128), 256, 0, stream>>>(
        omid, omid, omid, HUGE, HUGE, 256, Wo, nullptr, 256, bo, nullptr,
        out, 256, 256, 256);
}

// Round 4
// 70.186 us; speedup vs baseline: 1.4288x; 1.4288x over previous
//
#include <hip/hip_runtime.h>
#include <stdint.h>

// B=8, Q=2048, D=256, H=8, L=3, P=4, HD=32
// vproj rows: level-major, T={2048,1024,512}, LOFF={0,16384,24576}, total 28672

typedef __attribute__((ext_vector_type(8))) short bf16x8;
typedef __attribute__((ext_vector_type(8))) unsigned short u16x8;
typedef __attribute__((ext_vector_type(4))) float f32x4;

__device__ __forceinline__ unsigned short f2bf(float f) {
    union { float f; uint32_t u; } v; v.f = f;
    return (unsigned short)((v.u + 0x7FFFu + ((v.u >> 16) & 1u)) >> 16);  // RNE
}
__device__ __forceinline__ float bf2f(unsigned short u) {
    union { uint32_t u; float f; } v; v.u = ((uint32_t)u) << 16;
    return v.f;
}

// ---------------------------------------------------------------------------
// Generic GEMM: C[M,N] = A @ B + bias. bf16 MFMA, f32 accum.
// Tile 128x128, BK=32, 4 waves (2x2), wave tile 64x64.
// Epilogue: LDS-transposed coalesced stores (4 m-stages through Epi2[32][132]).
// A_BF16: A is bf16.  OUT_BF16: C is bf16.
// ---------------------------------------------------------------------------
template<bool A_BF16, bool OUT_BF16>
__global__ __launch_bounds__(256) void gemm_mfma_kernel(
    const void* __restrict__ A0v, const void* __restrict__ A1v, const void* __restrict__ A2v,
    int s0, int s1, int lda,
    const float* __restrict__ Bm, int ldb,
    const float* __restrict__ bias,
    void* __restrict__ Cv, int ldc, int K)
{
    __shared__ unsigned short Asub[4][128][8];  // 8 KB
    __shared__ unsigned short Bsub[4][128][8];  // 8 KB
    __shared__ float Epi2[32][132];             // 16.5 KB, pad->2-way banks only

    const int t = threadIdx.x;
    const int row0 = blockIdx.y * 128;
    const int col0 = blockIdx.x * 128;

    const void* Ap; int arow;
    if (row0 < s0)      { Ap = A0v; arow = row0; }
    else if (row0 < s1) { Ap = A1v; arow = row0 - s0; }
    else                { Ap = A2v; arow = row0 - s1; }

    const int ar = t >> 1, ah = t & 1;        // A staging: row, k-half
    const int bc = t & 127, bq = t >> 7;      // B staging: col, slot-pair

    const int w = t >> 6, lane = t & 63;
    const int wr = w >> 1, wc = w & 1;        // wave 2x2 -> 64x64 tile
    const int fr = lane & 15, sl = lane >> 4; // fragment row/col + k-slot

    f32x4 acc[4][4];
#pragma unroll
    for (int m = 0; m < 4; ++m)
#pragma unroll
        for (int n = 0; n < 4; ++n) acc[m][n] = (f32x4){0.f, 0.f, 0.f, 0.f};

    for (int k0 = 0; k0 < K; k0 += 32) {
#pragma unroll
        for (int q = 0; q < 2; ++q) {           // stage A
            const int slot = ah * 2 + q;
            if (A_BF16) {
                const unsigned short* Aps = (const unsigned short*)Ap;
                *reinterpret_cast<u16x8*>(&Asub[slot][ar][0]) =
                    *reinterpret_cast<const u16x8*>(&Aps[(size_t)(arow + ar) * lda + k0 + slot * 8]);
            } else {
                const float* Apf = (const float*)Ap;
                const float4 f0 = *reinterpret_cast<const float4*>(
                    &Apf[(size_t)(arow + ar) * lda + k0 + slot * 8]);
                const float4 f1 = *reinterpret_cast<const float4*>(
                    &Apf[(size_t)(arow + ar) * lda + k0 + slot * 8 + 4]);
                u16x8 pk;
                pk[0]=f2bf(f0.x); pk[1]=f2bf(f0.y); pk[2]=f2bf(f0.z); pk[3]=f2bf(f0.w);
                pk[4]=f2bf(f1.x); pk[5]=f2bf(f1.y); pk[6]=f2bf(f1.z); pk[7]=f2bf(f1.w);
                *reinterpret_cast<u16x8*>(&Asub[slot][ar][0]) = pk;
            }
        }
#pragma unroll
        for (int q = 0; q < 2; ++q) {           // stage B transposed (k-contig per col)
            const int slot = bq * 2 + q;
            u16x8 pk;
#pragma unroll
            for (int j = 0; j < 8; ++j)
                pk[j] = f2bf(Bm[(size_t)(k0 + slot * 8 + j) * ldb + col0 + bc]);
            *reinterpret_cast<u16x8*>(&Bsub[slot][bc][0]) = pk;
        }
        __syncthreads();

        bf16x8 bfrag[4];
#pragma unroll
        for (int n = 0; n < 4; ++n)
            bfrag[n] = *reinterpret_cast<bf16x8*>(&Bsub[sl][wc * 64 + n * 16 + fr][0]);
#pragma unroll
        for (int m = 0; m < 4; ++m) {
            bf16x8 afrag = *reinterpret_cast<bf16x8*>(&Asub[sl][wr * 64 + m * 16 + fr][0]);
#pragma unroll
            for (int n = 0; n < 4; ++n)
                acc[m][n] = __builtin_amdgcn_mfma_f32_16x16x32_bf16(afrag, bfrag[n], acc[m][n], 0, 0, 0);
        }
        __syncthreads();
    }

    // bias per output col of this wave
    float bs[4];
#pragma unroll
    for (int n = 0; n < 4; ++n) bs[n] = bias[col0 + wc * 64 + n * 16 + fr];

    // Epilogue: 4 m-stages through LDS -> coalesced stores.
    // acc[m][n][j] is (row_local = wr*64 + m*16 + sl*4 + j, col = wc*64 + n*16 + fr)
#pragma unroll
    for (int m = 0; m < 4; ++m) {
#pragma unroll
        for (int n = 0; n < 4; ++n)
#pragma unroll
            for (int j = 0; j < 4; ++j)
                Epi2[wr * 16 + sl * 4 + j][wc * 64 + n * 16 + fr] = acc[m][n][j] + bs[n];
        __syncthreads();
        if (OUT_BF16) {
            // 32 rows x 128 cols bf16: 512 short8 chunks, 2 per thread
#pragma unroll
            for (int i = 0; i < 2; ++i) {
                const int idx = t + i * 256;
                const int rb = idx >> 4, c8 = idx & 15;
                const int grow = row0 + m * 16 + (rb >> 4) * 64 + (rb & 15);
                u16x8 pk;
#pragma unroll
                for (int e = 0; e < 8; ++e) pk[e] = f2bf(Epi2[rb][c8 * 8 + e]);
                *reinterpret_cast<u16x8*>(
                    &((unsigned short*)Cv)[(size_t)grow * ldc + col0 + c8 * 8]) = pk;
            }
        } else {
            // 32 rows x 128 cols f32: 1024 float4 chunks, 4 per thread
#pragma unroll
            for (int i = 0; i < 4; ++i) {
                const int idx = t + i * 256;
                const int rb = idx >> 5, c4 = idx & 31;
                const int grow = row0 + m * 16 + (rb >> 4) * 64 + (rb & 15);
                const float4 o = *reinterpret_cast<const float4*>(&Epi2[rb][c4 * 4]);
                *reinterpret_cast<float4*>(
                    &((float*)Cv)[(size_t)grow * ldc + col0 + c4 * 4]) = o;
            }
        }
        __syncthreads();
    }
}

// ---------------------------------------------------------------------------
// Wcat pre-swizzle: bf16, layout [k0t][slot][col][kk] (k = k0t*32+slot*8+kk),
// i.e. exactly the GEMM's per-tile LDS staging order -> staging is memcpy.
// Also bcat[192] = [boff|baw] f32.
// ---------------------------------------------------------------------------
__global__ __launch_bounds__(256) void concat_w_kernel(
    const float* __restrict__ Woff, const float* __restrict__ Waw,
    const float* __restrict__ boff, const float* __restrict__ baw,
    unsigned short* __restrict__ wcat, float* __restrict__ bcat)
{
    const int id = blockIdx.x * 256 + threadIdx.x;    // 0..49151
    const int kk = id & 7;
    const int c2 = id >> 3;        // 0..6143
    const int col = c2 % 192;
    const int sb  = c2 / 192;      // 0..31
    const int k = (sb >> 2) * 32 + (sb & 3) * 8 + kk;
    const float v = (col < 96) ? Woff[k * 96 + col] : Waw[k * 96 + (col - 96)];
    wcat[id] = f2bf(v);
    if (blockIdx.x == 0 && threadIdx.x < 192)
        bcat[threadIdx.x] = (threadIdx.x < 96) ? boff[threadIdx.x] : baw[threadIdx.x - 96];
}

// ---------------------------------------------------------------------------
// Fused logits GEMM + per-head softmax + sidx.
// Tile: 64 queries x 192 cols (exact), grid 256, 4 waves 2x2, wave 32x96.
// Output rows[bq][0..95] = sidx, rows[bq][96..191] = aw (coalesced f4 stores).
// ---------------------------------------------------------------------------
__global__ __launch_bounds__(256) void gemm_logits_kernel(
    const float* __restrict__ query,           // [16384,256]
    const unsigned short* __restrict__ wcat,   // pre-swizzled bf16
    const float* __restrict__ bcat,            // [192]
    const float* __restrict__ refp,            // [16384]
    float* __restrict__ rows)                  // [16384,192]
{
    __shared__ unsigned short Asub[4][64][8];   // 4 KB
    __shared__ unsigned short Bsub[4][192][8];  // 12 KB
    __shared__ float Epi[64][196];              // 50.2 KB (196%32=4 -> 2-way banks)

    const int t = threadIdx.x;
    const int qrow0 = blockIdx.x * 64;

    const int w = t >> 6, lane = t & 63;
    const int wr = w >> 1, wc = w & 1;          // wave: 32 rows x 96 cols
    const int fr = lane & 15, sl = lane >> 4;

    f32x4 acc[2][6];
#pragma unroll
    for (int m = 0; m < 2; ++m)
#pragma unroll
        for (int n = 0; n < 6; ++n) acc[m][n] = (f32x4){0.f, 0.f, 0.f, 0.f};

    const int ar = t >> 2, as = t & 3;          // A staging: row 0..63, slot 0..3

    for (int k0t = 0; k0t < 8; ++k0t) {
        const int k0 = k0t * 32;
        {   // stage A: 64 rows x 32 k, f32 -> bf16
            const float* src = &query[(size_t)(qrow0 + ar) * 256 + k0 + as * 8];
            const float4 f0 = *reinterpret_cast<const float4*>(src);
            const float4 f1 = *reinterpret_cast<const float4*>(src + 4);
            u16x8 pk;
            pk[0]=f2bf(f0.x); pk[1]=f2bf(f0.y); pk[2]=f2bf(f0.z); pk[3]=f2bf(f0.w);
            pk[4]=f2bf(f1.x); pk[5]=f2bf(f1.y); pk[6]=f2bf(f1.z); pk[7]=f2bf(f1.w);
            *reinterpret_cast<u16x8*>(&Asub[as][ar][0]) = pk;
        }
        {   // stage B: pure 16B copies from pre-swizzled wcat
            const u16x8* src = reinterpret_cast<const u16x8*>(&wcat[(size_t)k0t * 6144]);
#pragma unroll
            for (int i = 0; i < 3; ++i) {
                const int c = t + i * 256;      // 0..767
                *reinterpret_cast<u16x8*>(&Bsub[c / 192][c % 192][0]) = src[c];
            }
        }
        __syncthreads();

        bf16x8 bfrag[6];
#pragma unroll
        for (int n = 0; n < 6; ++n)
            bfrag[n] = *reinterpret_cast<bf16x8*>(&Bsub[sl][wc * 96 + n * 16 + fr][0]);
#pragma unroll
        for (int m = 0; m < 2; ++m) {
            bf16x8 afrag = *reinterpret_cast<bf16x8*>(&Asub[sl][wr * 32 + m * 16 + fr][0]);
#pragma unroll
            for (int n = 0; n < 6; ++n)
                acc[m][n] = __builtin_amdgcn_mfma_f32_16x16x32_bf16(afrag, bfrag[n], acc[m][n], 0, 0, 0);
        }
        __syncthreads();
    }

    // acc -> Epi (logits + bias). (row = wr*32+m*16+sl*4+j, col = wc*96+n*16+fr)
#pragma unroll
    for (int n = 0; n < 6; ++n) {
        const int col = wc * 96 + n * 16 + fr;
        const float bsn = bcat[col];
#pragma unroll
        for (int m = 0; m < 2; ++m)
#pragma unroll
            for (int j = 0; j < 4; ++j)
                Epi[wr * 32 + m * 16 + sl * 4 + j][col] = acc[m][n][j] + bsn;
    }
    __syncthreads();

    // In-place per-head softmax (cols 96..191) + sidx (cols 0..95).
    // 512 (q,h) pairs; thread handles p = t and t+256.
#pragma unroll
    for (int i = 0; i < 2; ++i) {
        const int p = t + i * 256;
        const int q = p >> 3, h = p & 7;
        const float ref = refp[qrow0 + q];
        float* lg = &Epi[q][96 + h * 12];
        float mx = -1e30f;
#pragma unroll
        for (int jj = 0; jj < 12; ++jj) mx = fmaxf(mx, lg[jj]);
        float e[12]; float s = 0.f;
#pragma unroll
        for (int jj = 0; jj < 12; ++jj) { e[jj] = expf(lg[jj] - mx); s += e[jj]; }
        const float inv = 1.f / s;
#pragma unroll
        for (int jj = 0; jj < 12; ++jj) lg[jj] = e[jj] * inv;
        float* off = &Epi[q][h * 12];
#pragma unroll
        for (int jj = 0; jj < 12; ++jj) {
            const int l = jj >> 2;
            const int T = 2048 >> l;
            float pos = ref + off[jj] / (float)T;
            pos = fminf(fmaxf(pos, 0.f), 1.f);
            off[jj] = pos * (float)(T - 1);
        }
    }
    __syncthreads();

    // Coalesced writeout: 64 x 192 f32 = 3072 float4, 12 per thread.
#pragma unroll
    for (int i = 0; i < 12; ++i) {
        const int idx = t + i * 256;
        const int q = idx / 48, c4 = idx % 48;
        const float4 o = *reinterpret_cast<const float4*>(&Epi[q][c4 * 4]);
        *reinterpret_cast<float4*>(&rows[(size_t)(qrow0 + q) * 192 + c4 * 4]) = o;
    }
}

// ---------------------------------------------------------------------------
// Gather + lerp + weighted sum. rows[bq][j]=sidx, rows[bq][96+j]=aw.
// XCD swizzle: bq = (bid&7)*2048 + (bid>>3) -> per-XCD batch locality.
// ---------------------------------------------------------------------------
__global__ __launch_bounds__(256) void sample_kernel(
    const float* __restrict__ rows,            // [16384,192]  sidx | aw
    const unsigned short* __restrict__ vproj,  // [28672,128]  bf16, level-major
    unsigned short* __restrict__ out_mid)      // [16384,256]  bf16
{
    const int bid = blockIdx.x;
    const int bq = ((bid & 7) << 11) | (bid >> 3);
    const int b = bq >> 11;
    const int t = threadIdx.x;
    const int h = t >> 5, c = t & 31;
    __shared__ float srow[192];
    if (t < 192) srow[t] = rows[(size_t)bq * 192 + t];
    __syncthreads();
    float acc = 0.f;
#pragma unroll
    for (int l = 0; l < 3; ++l) {
        const int T = 2048 >> l;
        const int loff = (l == 0) ? 0 : ((l == 1) ? 16384 : 24576);
#pragma unroll
        for (int p = 0; p < 4; ++p) {
            const int j = h * 12 + l * 4 + p;
            const float wgt  = srow[96 + j];
            const float sidx = srow[j];
            int ifl = (int)sidx;
            ifl = min(max(ifl, 0), T - 2);
            const float wce = sidx - (float)ifl;
            const size_t base = ((size_t)(loff + b * T + ifl)) * 128 + p * 32 + c;
            const float vf = bf2f(vproj[base]);
            const float vc = bf2f(vproj[base + 128]);
            acc += wgt * (vf + wce * (vc - vf));
        }
    }
    out_mid[(size_t)bq * 256 + t] = f2bf(acc);
}

extern "C" void kernel_launch(void* const* d_in, const int* in_sizes, int n_in,
                              void* d_out, int out_size, void* d_ws, size_t ws_size,
                              hipStream_t stream) {
    (void)in_sizes; (void)n_in; (void)out_size; (void)ws_size;
    const float* query = (const float*)d_in[0];
    const float* refp  = (const float*)d_in[1];
    const float* v0    = (const float*)d_in[2];
    const float* v1    = (const float*)d_in[3];
    const float* v2    = (const float*)d_in[4];
    const float* Woff  = (const float*)d_in[5];
    const float* boff  = (const float*)d_in[6];
    const float* Waw   = (const float*)d_in[7];
    const float* baw   = (const float*)d_in[8];
    const float* Wv    = (const float*)d_in[9];
    const float* bv    = (const float*)d_in[10];
    const float* Wo    = (const float*)d_in[11];
    const float* bo    = (const float*)d_in[12];
    float* out = (float*)d_out;

    char* ws = (char*)d_ws;
    unsigned short* vproj = (unsigned short*)(ws);                      // 7,340,032 B
    float*          rows  = (float*)(ws + 7340032);                     // 12,582,912 B
    unsigned short* omid  = (unsigned short*)(ws + 7340032 + 12582912); // 8,388,608 B
    unsigned short* wcat  = (unsigned short*)(ws + 28311552);           // 98,304 B
    float*          bcat  = (float*)(ws + 28311552 + 98304);            // 768 B

    const int HUGE = 1 << 30;

    // K0: weight pre-swizzle (bf16, staging layout)
    concat_w_kernel<<<192, 256, 0, stream>>>(Woff, Waw, boff, baw, wcat, bcat);

    // K1: fused value projections (3 levels), bf16 out, coalesced epilogue.
    // Only cols 0..127 of Wv consumed (reference gathers head axis by p<4).
    gemm_mfma_kernel<false, true><<<dim3(1, 224), 256, 0, stream>>>(
        v0, v1, v2, 16384, 24576, 256, Wv, 256, bv, vproj, 128, 256);

    // K2: fused logits GEMM + softmax + sidx (rows: [sidx|aw])
    gemm_logits_kernel<<<256, 256, 0, stream>>>(query, wcat, bcat, refp, rows);

    // K3: gather + lerp + weighted sum
    sample_kernel<<<16384, 256, 0, stream>>>(rows, vproj, omid);

    // K4: output projection (A = bf16 omid), coalesced f32 epilogue
    gemm_mfma_kernel<true, false><<<dim3(2, 128), 256, 0, stream>>>(
        omid, omid, omid, HUGE, HUGE, 256, Wo, 256, bo, out, 256, 256);
}